// Round 3
// baseline (154.643 us; speedup 1.0000x reference)
//
#include <hip/hip_runtime.h>
#include <hip/hip_bf16.h>

// FlowNetC correlation via bf16 MFMA, fp32 accumulate. Two kernels:
//  1) conv_in2: in2 [b][c][y][x] fp32 -> in2t [b][y][x][c] bf16 (d_ws, 16.8 MB),
//     LDS tile transpose, memory-bound one-shot prepass.
//  2) corr_mfma: per block (b, y): S[x, col] = sum_c A[c,x] * W[c,col]
//     (A = in1 row (fp32->bf16 regs, built once), W = padded in2t row from LDS,
//     col = x + 2dx + 20), then out[dx,x] = S[x, x+2dx] / 256.
//     Staging per dy-row r is now 4 x dwordx4 contiguous global + 8 x ds_write_b64
//     per thread (was 32 scalar fp32 loads + repack -> the round-2 bottleneck).
//
// LDS B layout: [col][cd] bf16x2 dwords, col stride 134 (134 % 32 == 6; odd-ish
// stride keeps staging writes and b64 frag reads <=2-way; measured 7e5 conflicts).

typedef short    bf16x8 __attribute__((ext_vector_type(8)));
typedef float    f32x4  __attribute__((ext_vector_type(4)));
typedef unsigned u32x2  __attribute__((ext_vector_type(2)));

constexpr int CSTRIDE = 64 * 64;        // fp32 channel plane
constexpr int BSTRIDE = 256 * CSTRIDE;  // fp32 batch
constexpr int NCOLS   = 112;            // padded cols (104 used + guard)
constexpr int CSTR    = 134;            // dwords per col (128 data + 6 pad)

union BF2 { __hip_bfloat162 h; unsigned u; };
union BF1 { __hip_bfloat16 h; unsigned short u; };

__device__ inline unsigned pack_bf2(float lo, float hi) {
    BF2 cv;
    cv.h = __float22bfloat162_rn(make_float2(lo, hi));
    return cv.u;
}

// ---------------- prepass: in2 -> bf16 channel-last ----------------
__global__ __launch_bounds__(256)
void conv_in2(const float* __restrict__ in2, unsigned short* __restrict__ in2t)
{
    __shared__ unsigned short lt[64 * 66];   // [x][cc], row = 66 ushorts = 33 dwords
    const int tid = threadIdx.x;
    const int b = blockIdx.x & 7;
    const int y = blockIdx.x >> 3;
    const float* src = in2 + b * BSTRIDE + y * 64;            // + c*4096 + x
    unsigned* odw = reinterpret_cast<unsigned*>(in2t + (b * 64 + y) * (64 * 256));

    for (int c0 = 0; c0 < 256; c0 += 64) {
        __syncthreads();
#pragma unroll
        for (int it = 0; it < 16; ++it) {
            const int c = it * 4 + (tid >> 6);
            const int x = tid & 63;
            BF1 cv; cv.h = __float2bfloat16(src[(c0 + c) * CSTRIDE + x]);
            lt[x * 66 + c] = cv.u;
        }
        __syncthreads();
        const unsigned* ldw = reinterpret_cast<const unsigned*>(lt);
#pragma unroll
        for (int it = 0; it < 8; ++it) {
            const int flat = tid + 256 * it;   // 0..2047
            const int x  = flat >> 5;
            const int cp = flat & 31;
            odw[x * 128 + (c0 >> 1) + cp] = ldw[x * 33 + cp];
        }
    }
}

// ---------------- main correlation kernel ----------------
__global__ __launch_bounds__(512, 4)
void corr_mfma(const float* __restrict__ in1,
               const unsigned short* __restrict__ in2t,
               float* __restrict__ out)
{
    __shared__ __align__(16) unsigned blds[NCOLS * CSTR];  // 60,032 B
    __shared__ float slds[21 * 65];                        //  5,460 B

    const int tid  = threadIdx.x;
    const int lane = tid & 63;
    const int w    = tid >> 6;          // wave 0..7
    const int b    = blockIdx.x & 7;    // same-b blocks -> same XCD L2
    const int y    = blockIdx.x >> 3;

    const int cl = lane & 15;           // MFMA m/n lane index
    const int q  = lane >> 4;           // MFMA quad
    const int m  = w & 3;               // M-tile (x in [16m, 16m+16))
    const int nh = w >> 2;              // n-half

    const float* i1b = in1 + b * BSTRIDE;

    // ---- A fragments: A[m_row = cl][k_local = 8q + j], built once per block ----
    bf16x8 afrag[8];
#pragma unroll
    for (int k = 0; k < 8; ++k) {
        const float* p = i1b + (32 * k + 8 * q) * CSTRIDE + y * 64 + 16 * m + cl;
        float v[8];
#pragma unroll
        for (int j = 0; j < 8; ++j) v[j] = p[j * CSTRIDE];
#pragma unroll
        for (int j = 0; j < 4; ++j)
            ((unsigned*)&afrag[k])[j] = pack_bf2(v[2 * j], v[2 * j + 1]);
    }

    // ---- zero-pad cols 0..19 and 84..111 (cd 0..127), once per block ----
    for (int i = tid; i < 48 * 128; i += 512) {
        const int colz = i >> 7;
        const int col  = (colz < 20) ? colz : colz + 64;
        blds[col * CSTR + (i & 127)] = 0u;
    }

    for (int r = 0; r < 21; ++r) {
        const int yy = y + 2 * r - 20;
        const int ob = (b * 441 + r * 21) * CSTRIDE + y * 64;

        if (yy < 0 || yy > 63) {   // block-uniform: whole dy row is zero
            for (int i = tid; i < 21 * 64; i += 512)
                out[ob + (i >> 6) * CSTRIDE + (i & 63)] = 0.f;
            continue;
        }

        // ---- stage W_r from in2t: 32 KB contiguous row -> blds cols 20..83 ----
        {
            const uint4* src = reinterpret_cast<const uint4*>(
                in2t + (b * 64 + yy) * (64 * 256));
#pragma unroll
            for (int j = 0; j < 4; ++j) {
                const int seg = tid + 512 * j;    // 16-B segment id, 0..2047
                const int x   = seg >> 5;         // 32 segs per x
                const int cw  = (seg & 31) << 2;  // dword offset in col: 0..124
                const uint4 v = src[seg];
                unsigned* d = &blds[(x + 20) * CSTR + cw];
                *reinterpret_cast<u32x2*>(d)     = u32x2{v.x, v.y};
                *reinterpret_cast<u32x2*>(d + 2) = u32x2{v.z, v.w};
            }
        }
        __syncthreads();

        // ---- MFMA: S-tiles (m, n) for n = m+2nh, m+2nh+1 ----
#pragma unroll
        for (int nn = 0; nn < 2; ++nn) {
            const int n     = m + 2 * nh + nn;
            const int baddr = (16 * n + cl) * CSTR + 4 * q;   // + 16k, 8B aligned
            f32x4 acc = {0.f, 0.f, 0.f, 0.f};
#pragma unroll
            for (int k = 0; k < 8; ++k) {
                bf16x8 bfrag;
                ((u32x2*)&bfrag)[0] = *(const u32x2*)&blds[baddr + 16 * k];
                ((u32x2*)&bfrag)[1] = *(const u32x2*)&blds[baddr + 16 * k + 2];
                acc = __builtin_amdgcn_mfma_f32_16x16x32_bf16(afrag[k], bfrag, acc, 0, 0, 0);
            }
            // epilogue: D[row = 4q+i, col = cl]; gx = 16m+row, gcol = 16n+cl
            const int gcol = 16 * n + cl;
#pragma unroll
            for (int i = 0; i < 4; ++i) {
                const int gx = 16 * m + 4 * q + i;
                const int d2 = gcol - gx;                     // = 2*dx if valid
                if (d2 >= 0 && d2 <= 40 && !(d2 & 1))
                    slds[(d2 >> 1) * 65 + gx] = acc[i];
            }
        }
        __syncthreads();   // slds writes (all waves) -> slds reads (race fix)

        // ---- coalesced store of the 21x64 output rows for this r ----
        for (int i = tid; i < 21 * 64; i += 512) {
            const int dx = i >> 6, gx = i & 63;
            out[ob + dx * CSTRIDE + gx] = slds[dx * 65 + gx] * (1.f / 256.f);
        }
        __syncthreads();   // slds reads done before next-iter epilogue rewrites
    }
}

extern "C" void kernel_launch(void* const* d_in, const int* in_sizes, int n_in,
                              void* d_out, int out_size, void* d_ws, size_t ws_size,
                              hipStream_t stream) {
    const float* in1 = (const float*)d_in[0];
    const float* in2 = (const float*)d_in[1];
    float* out = (float*)d_out;
    unsigned short* in2t = (unsigned short*)d_ws;   // 8*64*64*256*2 B = 16.8 MB

    conv_in2<<<dim3(512), dim3(256), 0, stream>>>(in2, in2t);
    corr_mfma<<<dim3(512), dim3(512), 0, stream>>>(in1, in2t, out);
}

// Round 4
// 151.141 us; speedup vs baseline: 1.0232x; 1.0232x over previous
//
#include <hip/hip_runtime.h>
#include <hip/hip_bf16.h>

// FlowNetC correlation via bf16 MFMA, fp32 accumulate.
// out[b, r*21+dx, y, x] = (1/256) * sum_c in1[b,c,y,x] * in2[b,c, y+2r-20, x+2dx-20]
//
// Round-4 structure:
//  1) conv_in2 prepass: in2 fp32 -> in2t bf16 in FRAG-NATIVE chunks
//     [b][y][c8=c/8][x][c%8]: a 16x16x32-MFMA B-fragment (8 consecutive c at one x)
//     is ONE 16-B contiguous global load. 16.8 MB in d_ws.
//  2) corr_mfma: block = (b, y-pair {y0, y0+2}), 1024 thr (16 waves), 1 block/CU.
//     Wave w: tile (m = w&3, n = m + (w>>2)) -- exactly the 16 needed band tiles.
//     A-frags for BOTH y's live in VGPRs (64 regs, built once, reused 22 iters).
//     Per iter i (in2 row yy = y0-20+2i): 8 dwordx4 B-loads straight from L2
//     (b = blk&7 pins batch to one XCD; 2.1 MB slice fits its 4 MB L2), each
//     wfrag feeds 2 MFMAs (y-pair reuse halves W traffic/MFMA). No B-LDS at all
//     -> no staging barriers (round-3 was barrier/LDS-roundtrip serialized:
//     MfmaUtil 11%, VALUBusy 13%). Epilogue: diagonal gather via slds -> coalesced
//     stores, 2 barriers/iter.

typedef short    bf16x8 __attribute__((ext_vector_type(8)));
typedef float    f32x4  __attribute__((ext_vector_type(4)));

constexpr int CSTRIDE = 64 * 64;        // fp32 channel plane
constexpr int BSTRIDE = 256 * CSTRIDE;  // fp32 batch

union BF2 { __hip_bfloat162 h; unsigned u; };
union BF1 { __hip_bfloat16 h; unsigned short u; };

__device__ inline unsigned pack_bf2(float lo, float hi) {
    BF2 cv;
    cv.h = __float22bfloat162_rn(make_float2(lo, hi));
    return cv.u;
}

__device__ __align__(16) const uint4 ZERO16 = {0u, 0u, 0u, 0u};

// ---------------- prepass: in2 -> bf16 frag-native chunks ----------------
__global__ __launch_bounds__(256)
void conv_in2(const float* __restrict__ in2, unsigned* __restrict__ out_dw)
{
    __shared__ unsigned short lt[64 * 66];   // [x][c_local], 66 keeps banks spread
    const int tid = threadIdx.x;
    const int b = blockIdx.x & 7;
    const int y = blockIdx.x >> 3;
    const float* src = in2 + b * BSTRIDE + y * 64;            // + c*4096 + x
    unsigned* odw = out_dw + (b * 64 + y) * 8192;             // 32 KB per (b,y)

    for (int c0 = 0; c0 < 256; c0 += 64) {
        __syncthreads();
#pragma unroll
        for (int it = 0; it < 16; ++it) {
            const int c = it * 4 + (tid >> 6);
            const int x = tid & 63;
            BF1 cv; cv.h = __float2bfloat16(src[(c0 + c) * CSTRIDE + x]);
            lt[x * 66 + c] = cv.u;
        }
        __syncthreads();
        const unsigned* ldw = reinterpret_cast<const unsigned*>(lt);
#pragma unroll
        for (int it = 0; it < 8; ++it) {
            const int d   = tid + 256 * it;   // 0..2047 dwords this c0-chunk
            const int c8g = d >> 8;           // 0..7   (local c8)
            const int x   = (d >> 2) & 63;
            const int cd2 = d & 3;            // dword within 16-B chunk
            // dest chunk (c8 = c0/8 + c8g, x): 4 dwords; writes are contiguous
            odw[((c0 >> 3) + c8g) * 256 + x * 4 + cd2] = ldw[x * 33 + c8g * 4 + cd2];
        }
    }
}

// ---------------- main correlation kernel ----------------
__global__ __launch_bounds__(1024, 4)
void corr_mfma(const float* __restrict__ in1,
               const uint4* __restrict__ in2t,
               float* __restrict__ out)
{
    __shared__ float slds[2][21 * 65];   // 10.9 KB, per y-half

    const int tid  = threadIdx.x;
    const int lane = tid & 63;
    const int w    = tid >> 6;          // wave 0..15
    const int cl   = lane & 15;         // MFMA m/n lane index
    const int q    = lane >> 4;         // MFMA quad
    const int m    = w & 3;             // M-tile: gx in [16m, 16m+16)
    const int n    = m + (w >> 2);      // N-tile: col in [16n, 16n+16), n in 0..6
    const int b    = blockIdx.x & 7;    // batch -> XCD affinity
    const int p    = blockIdx.x >> 3;   // 0..31
    const int y0   = 4 * (p >> 1) + (p & 1);   // pair (y0, y0+2), covers all y

    // ---- A fragments for both y's: af[h][k] = in1[b, 32k+8q+j, y0+2h, 16m+cl] ----
    bf16x8 af[2][8];
#pragma unroll
    for (int h = 0; h < 2; ++h) {
        const float* pb = in1 + b * BSTRIDE + (y0 + 2 * h) * 64 + 16 * m + cl
                        + 8 * q * CSTRIDE;
#pragma unroll
        for (int k = 0; k < 8; ++k) {
            const float* pp = pb + 32 * k * CSTRIDE;
            float v[8];
#pragma unroll
            for (int j = 0; j < 8; ++j) v[j] = pp[j * CSTRIDE];
#pragma unroll
            for (int j = 0; j < 4; ++j)
                ((unsigned*)&af[h][k])[j] = pack_bf2(v[2 * j], v[2 * j + 1]);
        }
    }

    const int  x    = 16 * n + cl - 20;              // W col -> in2 x (may be OOB=0)
    const bool xok  = (x >= 0) && (x < 64);
    const int  gcol = 16 * n + cl;

    for (int i = 0; i < 22; ++i) {
        const int  yy      = y0 - 20 + 2 * i;
        const bool compute = (yy >= 0) && (yy < 64);

        if (compute) {
            const uint4* src = in2t + (b * 64 + yy) * 2048 + x;   // + (4k+q)*64
            f32x4 acc0 = {0.f, 0.f, 0.f, 0.f};
            f32x4 acc1 = {0.f, 0.f, 0.f, 0.f};
#pragma unroll
            for (int k = 0; k < 8; ++k) {
                const uint4* pk = xok ? (src + (4 * k + q) * 64) : &ZERO16;
                const uint4  wv = *pk;
                const bf16x8 bf = __builtin_bit_cast(bf16x8, wv);
                acc0 = __builtin_amdgcn_mfma_f32_16x16x32_bf16(af[0][k], bf, acc0, 0, 0, 0);
                acc1 = __builtin_amdgcn_mfma_f32_16x16x32_bf16(af[1][k], bf, acc1, 0, 0, 0);
            }
            // diagonal gather: D[row=4q+i4][col=cl]; gx = 16m+4q+i4, d2 = gcol-gx
#pragma unroll
            for (int i4 = 0; i4 < 4; ++i4) {
                const int gx = 16 * m + 4 * q + i4;
                const int d2 = gcol - gx;
                if (d2 >= 0 && d2 <= 40 && !(d2 & 1)) {
                    slds[0][(d2 >> 1) * 65 + gx] = acc0[i4];
                    slds[1][(d2 >> 1) * 65 + gx] = acc1[i4];
                }
            }
        }
        __syncthreads();

        // half0 -> (y0, r=i), half1 -> (y0+2, r=i-1); coalesced stores
        const int r0 = i, r1 = i - 1;
#pragma unroll
        for (int t3 = 0; t3 < 3; ++t3) {
            const int t = tid + 1024 * t3;
            if (t < 2 * 21 * 64) {
                const int h  = (t >= 1344) ? 1 : 0;
                const int u  = t - 1344 * h;
                const int dx = u >> 6, gx = u & 63;
                const int r  = h ? r1 : r0;
                if (r >= 0 && r <= 20) {
                    const float val = compute ? slds[h][dx * 65 + gx] * (1.f / 256.f)
                                              : 0.f;
                    out[((b * 441 + r * 21 + dx) * 64 + y0 + 2 * h) * 64 + gx] = val;
                }
            }
        }
        __syncthreads();
    }
}

extern "C" void kernel_launch(void* const* d_in, const int* in_sizes, int n_in,
                              void* d_out, int out_size, void* d_ws, size_t ws_size,
                              hipStream_t stream) {
    const float* in1 = (const float*)d_in[0];
    const float* in2 = (const float*)d_in[1];
    float* out = (float*)d_out;

    conv_in2<<<dim3(512), dim3(256), 0, stream>>>(in2, (unsigned*)d_ws);
    corr_mfma<<<dim3(256), dim3(1024), 0, stream>>>(in1, (const uint4*)d_ws, out);
}